// Round 1
// baseline (1786.038 us; speedup 1.0000x reference)
//
#include <hip/hip_runtime.h>
#include <hip/hip_bf16.h>

#define BB 8
#define TT_TOK 8192
#define DD 512
#define HH 4
#define HD 128
#define PP 24
#define TOPK 12
#define TEMP 0.07f
#define NC 16          // chunks over T
#define TC 512         // tokens per chunk
#define TILE 32        // tokens per tile
#define NTILE (TC / TILE)

// ws layout (floats):
// qhs   [H][P][HD]            @ 0        (12288)
// ml    [B][H][NC][P][2]      @ 12288    (24576)
// xbar  [B][H][NC][P][DD]     @ 36864    (6291456)
// proto_t [B][P][DD]          @ 6328320  (98304)
// total 6426624 floats = 25.7 MB

// ---------------- Qh precompute: Qp = proto @ Wq.T, per-head l2norm, fold 1/TEMP ----
__global__ __launch_bounds__(256) void qh_kernel(
    const float* __restrict__ proto, const float* __restrict__ Wq, float* __restrict__ qhs)
{
  const int p = blockIdx.x, tid = threadIdx.x;
  __shared__ float prow[DD];
  __shared__ float qp[DD];
  __shared__ float np[HH][8];
  __shared__ float nb[HH];
  prow[tid] = proto[(size_t)p * DD + tid];
  prow[tid + 256] = proto[(size_t)p * DD + tid + 256];
  __syncthreads();
#pragma unroll
  for (int i = 0; i < 2; ++i) {
    int dd = tid + i * 256;
    const float* w = Wq + (size_t)dd * DD;
    float s = 0.f;
    for (int d = 0; d < DD; ++d) s += prow[d] * w[d];
    qp[dd] = s;
  }
  __syncthreads();
  {
    int hh = tid >> 3, pr = tid & 7;
    if (hh < HH) {
      float s = 0.f;
      for (int k = 0; k < 16; ++k) { float v = qp[hh * HD + pr * 16 + k]; s += v * v; }
      np[hh][pr] = s;
    }
  }
  __syncthreads();
  if (tid < HH) {
    float s = 0.f;
    for (int k = 0; k < 8; ++k) s += np[tid][k];
    nb[tid] = 1.f / (fmaxf(sqrtf(s), 1e-12f) * TEMP);
  }
  __syncthreads();
#pragma unroll
  for (int i = 0; i < 2; ++i) {
    int dd = tid + i * 256;
    int hh = dd >> 7, jj = dd & 127;
    qhs[((size_t)hh * PP + p) * HD + jj] = qp[dd] * nb[hh];
  }
}

// ---------------- fused LN + K-proj + online softmax + xn-accumulate (per b,h,chunk) ----
__global__ __launch_bounds__(256) void attn_partial(
    const float* __restrict__ x, const float* __restrict__ ln_g, const float* __restrict__ ln_b,
    const float* __restrict__ Wk, const float* __restrict__ qhs,
    float* __restrict__ ml, float* __restrict__ xbar)
{
  const int tid = threadIdx.x;
  const int blk = blockIdx.x;
  const int c = blk % NC;
  const int h = (blk / NC) % HH;
  const int b = blk / (NC * HH);
  const int hbase = h * HD;

  __shared__ float xs[TILE][DD + 4];     // 66048 B, xn tile (f32, padded rows)
  __shared__ float wks[32][HD + 4];      // 16896 B, Wk k-slice transposed [dk][j]
  __shared__ float qs[PP][HD];           // 12288 B
  __shared__ float sbuf[PP][TILE];       // 3072 B
  __shared__ float wbuf[PP][TILE];       // 3072 B
  __shared__ float red[TILE][16];        // 2048 B
  __shared__ float mus[TILE], invs[TILE];
  __shared__ float fbuf[PP], mArr[PP], lArr[PP];

  for (int i = tid; i < PP * HD; i += 256) qs[i >> 7][i & 127] = qhs[(size_t)h * PP * HD + i];
  if (tid < PP) { mArr[tid] = -1e30f; lArr[tid] = 0.f; }

  float acc0[PP], acc1[PP];
#pragma unroll
  for (int p = 0; p < PP; ++p) { acc0[p] = 0.f; acc1[p] = 0.f; }
  const int d0 = tid * 2;

  const int tg = tid >> 4;   // 0..15 -> token pair
  const int jg = tid & 15;   // 0..15 -> 8 j's
  const int t0 = tg * 2, t1 = t0 + 1;
  const int jb = jg * 8;

  for (int tile = 0; tile < NTILE; ++tile) {
    const int trow0 = c * TC + tile * TILE;
    __syncthreads();   // protect xs (read in prev accumulate) before restage
    {
      const float* xsrc = x + ((size_t)b * TT_TOK + trow0) * DD;
#pragma unroll
      for (int i = 0; i < 16; ++i) {
        int flat = (i * 256 + tid) * 4;
        int r = flat >> 9, cc2 = flat & 511;
        *reinterpret_cast<float4*>(&xs[r][cc2]) =
            *reinterpret_cast<const float4*>(xsrc + (size_t)r * DD + cc2);
      }
    }
    __syncthreads();
    {   // LN stats: 8 threads per row
      int r = tid >> 3, part = tid & 7;
      float s = 0.f, s2 = 0.f;
#pragma unroll 8
      for (int k = 0; k < 64; ++k) { float v = xs[r][part * 64 + k]; s += v; s2 += v * v; }
      red[r][part] = s; red[r][8 + part] = s2;
    }
    __syncthreads();
    if (tid < TILE) {
      float s = 0.f, s2 = 0.f;
#pragma unroll
      for (int k = 0; k < 8; ++k) { s += red[tid][k]; s2 += red[tid][8 + k]; }
      float mu = s * (1.f / DD);
      float var = s2 * (1.f / DD) - mu * mu;
      mus[tid] = mu; invs[tid] = rsqrtf(var + 1e-5f);
    }
    __syncthreads();
#pragma unroll
    for (int i = 0; i < 16; ++i) {   // normalize in place
      int flat = (i * 256 + tid) * 4;
      int r = flat >> 9, cc2 = flat & 511;
      float4 v = *reinterpret_cast<float4*>(&xs[r][cc2]);
      float4 g = *reinterpret_cast<const float4*>(ln_g + cc2);
      float4 be = *reinterpret_cast<const float4*>(ln_b + cc2);
      float mu = mus[r], iv = invs[r];
      v.x = (v.x - mu) * iv * g.x + be.x;
      v.y = (v.y - mu) * iv * g.y + be.y;
      v.z = (v.z - mu) * iv * g.z + be.z;
      v.w = (v.w - mu) * iv * g.w + be.w;
      *reinterpret_cast<float4*>(&xs[r][cc2]) = v;
    }
    __syncthreads();

    // ---- K tile GEMM: K[t][j] = sum_d xn[t][d] * Wk[hbase+j][d], micro 2t x 8j ----
    float ka0[8], ka1[8];
#pragma unroll
    for (int q = 0; q < 8; ++q) { ka0[q] = 0.f; ka1[q] = 0.f; }
    for (int ks = 0; ks < DD / 32; ++ks) {
      {
        int j = tid >> 1, dkb = (tid & 1) * 16;
        const float* wrow = Wk + (size_t)(hbase + j) * DD + ks * 32 + dkb;
#pragma unroll
        for (int q = 0; q < 4; ++q) {
          float4 v = *reinterpret_cast<const float4*>(wrow + q * 4);
          wks[dkb + q * 4 + 0][j] = v.x;
          wks[dkb + q * 4 + 1][j] = v.y;
          wks[dkb + q * 4 + 2][j] = v.z;
          wks[dkb + q * 4 + 3][j] = v.w;
        }
      }
      __syncthreads();
#pragma unroll
      for (int dk = 0; dk < 32; ++dk) {
        float a0 = xs[t0][ks * 32 + dk];
        float a1 = xs[t1][ks * 32 + dk];
        float4 b0 = *reinterpret_cast<float4*>(&wks[dk][jb]);
        float4 b1v = *reinterpret_cast<float4*>(&wks[dk][jb + 4]);
        ka0[0] += a0 * b0.x;  ka0[1] += a0 * b0.y;  ka0[2] += a0 * b0.z;  ka0[3] += a0 * b0.w;
        ka0[4] += a0 * b1v.x; ka0[5] += a0 * b1v.y; ka0[6] += a0 * b1v.z; ka0[7] += a0 * b1v.w;
        ka1[0] += a1 * b0.x;  ka1[1] += a1 * b0.y;  ka1[2] += a1 * b0.z;  ka1[3] += a1 * b0.w;
        ka1[4] += a1 * b1v.x; ka1[5] += a1 * b1v.y; ka1[6] += a1 * b1v.z; ka1[7] += a1 * b1v.w;
      }
      __syncthreads();
    }

    // ---- per-token norms (reduce over 16 lanes sharing tg) ----
    float n0 = 0.f, n1 = 0.f;
#pragma unroll
    for (int q = 0; q < 8; ++q) { n0 += ka0[q] * ka0[q]; n1 += ka1[q] * ka1[q]; }
#pragma unroll
    for (int msk = 1; msk < 16; msk <<= 1) { n0 += __shfl_xor(n0, msk); n1 += __shfl_xor(n1, msk); }
    const float inv0 = 1.f / fmaxf(sqrtf(n0), 1e-12f);
    const float inv1 = 1.f / fmaxf(sqrtf(n1), 1e-12f);

    // ---- scores s[p][t] = (qhs[p] . K[t]) / ||K[t]|| ----
    float sp0[PP], sp1[PP];
#pragma unroll
    for (int p = 0; p < PP; ++p) {
      const float4 q0 = *reinterpret_cast<const float4*>(&qs[p][jb]);
      const float4 q1 = *reinterpret_cast<const float4*>(&qs[p][jb + 4]);
      sp0[p] = q0.x * ka0[0] + q0.y * ka0[1] + q0.z * ka0[2] + q0.w * ka0[3]
             + q1.x * ka0[4] + q1.y * ka0[5] + q1.z * ka0[6] + q1.w * ka0[7];
      sp1[p] = q0.x * ka1[0] + q0.y * ka1[1] + q0.z * ka1[2] + q0.w * ka1[3]
             + q1.x * ka1[4] + q1.y * ka1[5] + q1.z * ka1[6] + q1.w * ka1[7];
    }
#pragma unroll
    for (int p = 0; p < PP; ++p) {
#pragma unroll
      for (int msk = 1; msk < 16; msk <<= 1) {
        sp0[p] += __shfl_xor(sp0[p], msk);
        sp1[p] += __shfl_xor(sp1[p], msk);
      }
      sp0[p] *= inv0; sp1[p] *= inv1;
    }
#pragma unroll
    for (int p = 0; p < PP; ++p) {
      if (jg == (p & 15)) { sbuf[p][t0] = sp0[p]; sbuf[p][t1] = sp1[p]; }
    }
    __syncthreads();

    // ---- online softmax state update (24 threads) ----
    if (tid < PP) {
      const int p = tid;
      float mx = -1e30f;
#pragma unroll
      for (int t = 0; t < TILE; ++t) mx = fmaxf(mx, sbuf[p][t]);
      float mnew = fmaxf(mArr[p], mx);
      float f = expf(mArr[p] - mnew);
      float ls = 0.f;
#pragma unroll
      for (int t = 0; t < TILE; ++t) { float w = expf(sbuf[p][t] - mnew); wbuf[p][t] = w; ls += w; }
      lArr[p] = lArr[p] * f + ls;
      mArr[p] = mnew;
      fbuf[p] = f;
    }
    __syncthreads();

    // ---- rescale + accumulate xbar[p][d] += w[p][t]*xn[t][d] ----
#pragma unroll
    for (int p = 0; p < PP; ++p) { float f = fbuf[p]; acc0[p] *= f; acc1[p] *= f; }
    for (int t4 = 0; t4 < TILE; t4 += 4) {
      float2 xv0 = *reinterpret_cast<float2*>(&xs[t4 + 0][d0]);
      float2 xv1 = *reinterpret_cast<float2*>(&xs[t4 + 1][d0]);
      float2 xv2 = *reinterpret_cast<float2*>(&xs[t4 + 2][d0]);
      float2 xv3 = *reinterpret_cast<float2*>(&xs[t4 + 3][d0]);
#pragma unroll
      for (int p = 0; p < PP; ++p) {
        float4 w = *reinterpret_cast<float4*>(&wbuf[p][t4]);
        acc0[p] += w.x * xv0.x + w.y * xv1.x + w.z * xv2.x + w.w * xv3.x;
        acc1[p] += w.x * xv0.y + w.y * xv1.y + w.z * xv2.y + w.w * xv3.y;
      }
    }
  }

  // ---- write chunk partials ----
  __syncthreads();
  const size_t mlbase = ((((size_t)b * HH + h) * NC + c) * PP) * 2;
  if (tid < PP) { ml[mlbase + tid * 2] = mArr[tid]; ml[mlbase + tid * 2 + 1] = lArr[tid]; }
  const size_t abase = ((((size_t)b * HH + h) * NC + c) * PP) * DD;
#pragma unroll
  for (int p = 0; p < PP; ++p) {
    float2 v = make_float2(acc0[p], acc1[p]);
    *reinterpret_cast<float2*>(&xbar[abase + (size_t)p * DD + d0]) = v;
  }
}

// ---------------- combine chunk partials, apply Wv: proto_t[b][p][h*HD+j] ----
__global__ __launch_bounds__(256) void reduce_proto(
    const float* __restrict__ ml, const float* __restrict__ xbar,
    const float* __restrict__ Wv, float* __restrict__ proto_t)
{
  const int tid = threadIdx.x;
  const int blk = blockIdx.x;
  const int p = blk % PP;
  const int h = (blk / PP) % HH;
  const int b = blk / (PP * HH);

  __shared__ float fch[NC];
  __shared__ float LinvS;
  __shared__ float xbs[DD];
  __shared__ float part[256];

  if (tid == 0) {
    float mstar = -1e30f;
    for (int cc = 0; cc < NC; ++cc) {
      size_t idx = ((((size_t)b * HH + h) * NC + cc) * PP + p) * 2;
      mstar = fmaxf(mstar, ml[idx]);
    }
    float L = 0.f;
    for (int cc = 0; cc < NC; ++cc) {
      size_t idx = ((((size_t)b * HH + h) * NC + cc) * PP + p) * 2;
      float f = expf(ml[idx] - mstar);
      fch[cc] = f;
      L += ml[idx + 1] * f;
    }
    LinvS = 1.f / fmaxf(L, 1e-30f);
  }
  __syncthreads();
  float a0 = 0.f, a1 = 0.f;
  for (int cc = 0; cc < NC; ++cc) {
    float f = fch[cc];
    const float* src = xbar + ((((size_t)b * HH + h) * NC + cc) * PP + p) * DD;
    a0 += f * src[tid];
    a1 += f * src[tid + 256];
  }
  xbs[tid] = a0; xbs[tid + 256] = a1;
  __syncthreads();
  const float Linv = LinvS;
  const int j = tid & 127, halfsel = tid >> 7;
  const float* wrow = Wv + (size_t)(h * HD + j) * DD + halfsel * 256;
  const float* xh = &xbs[halfsel * 256];
  float s = 0.f;
#pragma unroll 4
  for (int d = 0; d < 256; ++d) s += xh[d] * wrow[d];
  part[tid] = s;
  __syncthreads();
  if (tid < 128) {
    proto_t[((size_t)b * PP + p) * DD + h * HD + tid] = (part[tid] + part[tid + 128]) * Linv;
  }
}

// ---------------- proto scores, stable top-k, mean, SiLU MLP ----
__global__ __launch_bounds__(256) void final_mlp(
    const float* __restrict__ proto_t, const float* __restrict__ W1, const float* __restrict__ b1,
    const float* __restrict__ W2, const float* __restrict__ b2, float* __restrict__ out)
{
  const int b = blockIdx.x, tid = threadIdx.x;
  __shared__ float pt[PP][DD];
  __shared__ float spart[PP][8];
  __shared__ float sc[PP];
  __shared__ int sel[PP];
  __shared__ float zb[DD];
  __shared__ float hb[DD];
  for (int i = tid; i < PP * DD; i += 256) pt[i >> 9][i & 511] = proto_t[(size_t)b * PP * DD + i];
  __syncthreads();
  {
    int p = tid >> 3, pr = tid & 7;
    if (p < PP) {
      float s = 0.f;
      for (int k = 0; k < 64; ++k) { float v = pt[p][pr * 64 + k]; s += v * v; }
      spart[p][pr] = s;
    }
  }
  __syncthreads();
  if (tid < PP) {
    float s = 0.f;
    for (int k = 0; k < 8; ++k) s += spart[tid][k];
    sc[tid] = s;
  }
  __syncthreads();
  if (tid < PP) {
    float sv = sc[tid]; int rank = 0;
    for (int q = 0; q < PP; ++q) { float so = sc[q]; if (so > sv || (so == sv && q < tid)) ++rank; }
    sel[tid] = (rank < TOPK) ? 1 : 0;
  }
  __syncthreads();
  {
    float z0 = 0.f, z1 = 0.f;
#pragma unroll
    for (int p = 0; p < PP; ++p)
      if (sel[p]) { z0 += pt[p][tid]; z1 += pt[p][tid + 256]; }
    zb[tid] = z0 * (1.f / TOPK); zb[tid + 256] = z1 * (1.f / TOPK);
  }
  __syncthreads();
#pragma unroll
  for (int i = 0; i < 2; ++i) {
    int jj = tid + i * 256;
    const float* w = W1 + (size_t)jj * DD;
    float s = 0.f;
    for (int d = 0; d < DD; ++d) s += zb[d] * w[d];
    s += b1[jj];
    hb[jj] = s / (1.f + expf(-s));   // silu
  }
  __syncthreads();
#pragma unroll
  for (int i = 0; i < 2; ++i) {
    int jj = tid + i * 256;
    const float* w = W2 + (size_t)jj * DD;
    float s = 0.f;
    for (int d = 0; d < DD; ++d) s += hb[d] * w[d];
    out[(size_t)b * DD + jj] = s + b2[jj];
  }
}

extern "C" void kernel_launch(void* const* d_in, const int* in_sizes, int n_in,
                              void* d_out, int out_size, void* d_ws, size_t ws_size,
                              hipStream_t stream)
{
  const float* x    = (const float*)d_in[0];
  const float* prt  = (const float*)d_in[1];
  const float* ln_g = (const float*)d_in[2];
  const float* ln_b = (const float*)d_in[3];
  const float* Wq   = (const float*)d_in[4];
  const float* Wk   = (const float*)d_in[5];
  const float* Wv   = (const float*)d_in[6];
  const float* W1   = (const float*)d_in[7];
  const float* b1   = (const float*)d_in[8];
  const float* W2   = (const float*)d_in[9];
  const float* b2   = (const float*)d_in[10];
  float* out = (float*)d_out;
  float* ws = (float*)d_ws;

  float* qhs = ws;                 // 12288
  float* ml  = ws + 12288;         // 24576
  float* xb  = ws + 36864;         // 6291456
  float* pt  = ws + 6328320;       // 98304

  qh_kernel<<<PP, 256, 0, stream>>>(prt, Wq, qhs);
  attn_partial<<<BB * HH * NC, 256, 0, stream>>>(x, ln_g, ln_b, Wk, qhs, ml, xb);
  reduce_proto<<<BB * HH * PP, 256, 0, stream>>>(ml, xb, Wv, pt);
  final_mlp<<<BB, 256, 0, stream>>>(pt, W1, b1, W2, b2, out);
}

// Round 2
// 595.571 us; speedup vs baseline: 2.9989x; 2.9989x over previous
//
#include <hip/hip_runtime.h>
#include <hip/hip_bf16.h>

#define BB 8
#define TSEQ 8192
#define DDIM 512
#define NH 4
#define HDIM 128
#define NP 24
#define NPAD 32
#define NTOPK 12
#define NCHUNK 16
#define TCHUNK 512
#define TTILE 64
#define NTILES 8

typedef _Float16 half8_t __attribute__((ext_vector_type(8)));
typedef _Float16 half4_t __attribute__((ext_vector_type(4)));
typedef float f32x4_t __attribute__((ext_vector_type(4)));

#define MFMA(a, b, c) __builtin_amdgcn_mfma_f32_16x16x32_f16((a), (b), (c), 0, 0, 0)

// ws layout (float units):
// qhs    @ 0        (12288)   [H][P][HD] f32, l2norm + 1/TEMP folded
// ml     @ 12288    (32768)   [512 blk][32][2] f32
// xbar   @ 45056    (8388608) [512 blk][32][512] f32
// pt     @ 8433664  (98304)   [B][P][D] f32
// wk16   @ 8531968  (131072 f32 = 262144 f16)  [512][512] f16
// wqk16  @ 8663040  (32768 f32 = 65536 f16)    [H][32][512] f16

// ---------------- Qh precompute: Qp = proto @ Wq.T, per-head l2norm, fold 1/TEMP ----
__global__ __launch_bounds__(256) void qh_kernel(
    const float* __restrict__ proto, const float* __restrict__ Wq, float* __restrict__ qhs)
{
  const int p = blockIdx.x, tid = threadIdx.x;
  __shared__ float prow[DDIM];
  __shared__ float qp[DDIM];
  __shared__ float np[NH][8];
  __shared__ float nb[NH];
  prow[tid] = proto[(size_t)p * DDIM + tid];
  prow[tid + 256] = proto[(size_t)p * DDIM + tid + 256];
  __syncthreads();
#pragma unroll
  for (int i = 0; i < 2; ++i) {
    int dd = tid + i * 256;
    const float* wr = Wq + (size_t)dd * DDIM;
    float s = 0.f;
    for (int d = 0; d < DDIM; ++d) s += prow[d] * wr[d];
    qp[dd] = s;
  }
  __syncthreads();
  {
    int hh = tid >> 3, pr = tid & 7;
    if (hh < NH) {
      float s = 0.f;
      for (int k = 0; k < 16; ++k) { float v = qp[hh * HDIM + pr * 16 + k]; s += v * v; }
      np[hh][pr] = s;
    }
  }
  __syncthreads();
  if (tid < NH) {
    float s = 0.f;
    for (int k = 0; k < 8; ++k) s += np[tid][k];
    nb[tid] = 1.f / (fmaxf(sqrtf(s), 1e-12f) * 0.07f);
  }
  __syncthreads();
#pragma unroll
  for (int i = 0; i < 2; ++i) {
    int dd = tid + i * 256;
    int hh = dd >> 7, jj = dd & 127;
    qhs[((size_t)hh * NP + p) * HDIM + jj] = qp[dd] * nb[hh];
  }
}

// ---------------- Wk -> f16 copy ----
__global__ __launch_bounds__(256) void wk16_kernel(
    const float* __restrict__ Wk, _Float16* __restrict__ wk16)
{
  const int row = blockIdx.x, tid = threadIdx.x;
  wk16[(size_t)row * 512 + tid]       = (_Float16)Wk[(size_t)row * 512 + tid];
  wk16[(size_t)row * 512 + tid + 256] = (_Float16)Wk[(size_t)row * 512 + tid + 256];
}

// ---------------- Wqk[h][p][d] = sum_j qhs[h][p][j] * Wk[h*128+j][d], f16 (pad p to 32) ----
__global__ __launch_bounds__(256) void wqk_kernel(
    const float* __restrict__ qhs, const float* __restrict__ Wk, _Float16* __restrict__ wqk16)
{
  const int blk = blockIdx.x, tid = threadIdx.x;
  const int p = blk & 31, h = blk >> 5;
  if (p >= NP) {
    wqk16[((size_t)(h * 32 + p)) * 512 + tid] = (_Float16)0.f;
    wqk16[((size_t)(h * 32 + p)) * 512 + tid + 256] = (_Float16)0.f;
    return;
  }
  __shared__ float qv[HDIM];
  if (tid < HDIM) qv[tid] = qhs[((size_t)h * NP + p) * HDIM + tid];
  __syncthreads();
  float s0 = 0.f, s1 = 0.f;
  for (int j = 0; j < HDIM; ++j) {
    float q = qv[j];
    const float* wr = Wk + (size_t)(h * 128 + j) * 512;
    s0 += q * wr[tid];
    s1 += q * wr[tid + 256];
  }
  wqk16[((size_t)(h * 32 + p)) * 512 + tid] = (_Float16)s0;
  wqk16[((size_t)(h * 32 + p)) * 512 + tid + 256] = (_Float16)s1;
}

// ---------------- fused LN + MFMA K-proj/scores + online softmax + MFMA accumulate ----
__global__ __launch_bounds__(256, 1) void attn2(
    const float* __restrict__ x, const float* __restrict__ ln_g, const float* __restrict__ ln_b,
    const _Float16* __restrict__ wk16, const _Float16* __restrict__ wqk16,
    float* __restrict__ ml, float* __restrict__ xbar)
{
  const int tid = threadIdx.x;
  const int l = tid & 63, w = tid >> 6;
  const int g = l >> 4, a = l & 15;
  const int blk = blockIdx.x;
  const int c = blk & 15, h = (blk >> 4) & 3, b = blk >> 6;

  // LDS
  __shared__ __align__(16) unsigned char xs_raw[64 * 1040];   // [64 t][520 f16], XOR-swizzled d-blocks
  __shared__ __align__(16) unsigned char xt_raw[512 * 144];   // [512 d][72 f16]  (64 t + pad)
  __shared__ __align__(16) unsigned char wl_raw[32 * 144];    // [32 p][72 f16]
  __shared__ float normp_s[4][64];
  __shared__ float invn_s[64];
  __shared__ float mArr_s[32], lArr_s[32];

  // ---- resident B-fragments: Wk j-slice (per wave) and Wqk (all waves) ----
  half8_t wkf[2][16], wqf[2][16];
#pragma unroll
  for (int nt = 0; nt < 2; ++nt)
#pragma unroll
    for (int kst = 0; kst < 16; ++kst) {
      wkf[nt][kst] = *reinterpret_cast<const half8_t*>(
          wk16 + (size_t)(h * 128 + w * 32 + nt * 16 + a) * 512 + kst * 32 + g * 8);
      wqf[nt][kst] = *reinterpret_cast<const half8_t*>(
          wqk16 + (size_t)(h * 32 + nt * 16 + a) * 512 + kst * 32 + g * 8);
    }

  f32x4_t acc3[2][8];
  const f32x4_t vzero = {0.f, 0.f, 0.f, 0.f};
#pragma unroll
  for (int pm = 0; pm < 2; ++pm)
#pragma unroll
    for (int nt = 0; nt < 8; ++nt) acc3[pm][nt] = vzero;

  if (tid < 32) { mArr_s[tid] = -1e30f; lArr_s[tid] = 0.f; }

  const int dpart = (16 * g) ^ (16 * (a & 3));   // swizzled d-offset for A-frag reads
  const float4* gp4 = reinterpret_cast<const float4*>(ln_g);
  const float4* bp4 = reinterpret_cast<const float4*>(ln_b);

  for (int tile = 0; tile < NTILES; ++tile) {
    __syncthreads();   // bar1: prev G3 done with xnT/wlds
    // ================= LN stage =================
    const float4* xp4 = reinterpret_cast<const float4*>(x) +
                        ((size_t)(b * TSEQ + c * TCHUNK + tile * TTILE)) * 128;
    float sA[4] = {0.f, 0.f, 0.f, 0.f}, sB[4] = {0.f, 0.f, 0.f, 0.f};
    half4_t praw[4][8];
#pragma unroll
    for (int tt = 0; tt < 4; ++tt) {
      const int tloc = 16 * w + 4 * g + tt;
#pragma unroll
      for (int i = 0; i < 8; ++i) {
        float4 xv = xp4[(size_t)tloc * 128 + a + 16 * i];
        sA[tt] += (xv.x + xv.y) + (xv.z + xv.w);
        sB[tt] += (xv.x * xv.x + xv.y * xv.y) + (xv.z * xv.z + xv.w * xv.w);
        half4_t pr;
        pr[0] = (_Float16)xv.x; pr[1] = (_Float16)xv.y;
        pr[2] = (_Float16)xv.z; pr[3] = (_Float16)xv.w;
        praw[tt][i] = pr;
      }
    }
#pragma unroll
    for (int m = 1; m < 16; m <<= 1) {
#pragma unroll
      for (int tt = 0; tt < 4; ++tt) {
        sA[tt] += __shfl_xor(sA[tt], m);
        sB[tt] += __shfl_xor(sB[tt], m);
      }
    }
    float muv[4], ivv[4];
#pragma unroll
    for (int tt = 0; tt < 4; ++tt) {
      float mu = sA[tt] * (1.f / 512.f);
      float var = sB[tt] * (1.f / 512.f) - mu * mu;
      muv[tt] = mu; ivv[tt] = rsqrtf(var + 1e-5f);
    }
#pragma unroll
    for (int i = 0; i < 8; ++i) {
      float4 gv = gp4[a + 16 * i], bv = bp4[a + 16 * i];
      float xnf[4][4];
#pragma unroll
      for (int tt = 0; tt < 4; ++tt) {
        half4_t pr = praw[tt][i];
        float q0 = ((float)pr[0] - muv[tt]) * ivv[tt];
        float q1 = ((float)pr[1] - muv[tt]) * ivv[tt];
        float q2 = ((float)pr[2] - muv[tt]) * ivv[tt];
        float q3 = ((float)pr[3] - muv[tt]) * ivv[tt];
        xnf[tt][0] = q0 * gv.x + bv.x;
        xnf[tt][1] = q1 * gv.y + bv.y;
        xnf[tt][2] = q2 * gv.z + bv.z;
        xnf[tt][3] = q3 * gv.w + bv.w;
        half4_t hx;
        hx[0] = (_Float16)xnf[tt][0]; hx[1] = (_Float16)xnf[tt][1];
        hx[2] = (_Float16)xnf[tt][2]; hx[3] = (_Float16)xnf[tt][3];
        const int tloc = 16 * w + 4 * g + tt;
        *reinterpret_cast<half4_t*>(xs_raw + tloc * 1040 + ((8 * a + 128 * i) ^ (16 * tt))) = hx;
      }
#pragma unroll
      for (int e = 0; e < 4; ++e) {
        half4_t hv;
        hv[0] = (_Float16)xnf[0][e]; hv[1] = (_Float16)xnf[1][e];
        hv[2] = (_Float16)xnf[2][e]; hv[3] = (_Float16)xnf[3][e];
        const int d = 4 * a + 64 * i + e;
        *reinterpret_cast<half4_t*>(xt_raw + d * 144 + 8 * (tid >> 4)) = hv;
      }
    }
    __syncthreads();   // bar2: xs/xnT ready

    // ================= GEMM1 (K) + GEMM2 (raw scores), fused k-loop =================
    f32x4_t kacc[4][2], qacc[4][2];
#pragma unroll
    for (int mt = 0; mt < 4; ++mt) { kacc[mt][0] = vzero; kacc[mt][1] = vzero;
                                     qacc[mt][0] = vzero; qacc[mt][1] = vzero; }
#pragma unroll
    for (int kst = 0; kst < 16; ++kst) {
#pragma unroll
      for (int mt = 0; mt < 4; ++mt) {
        half8_t af = *reinterpret_cast<const half8_t*>(
            xs_raw + mt * 16640 + a * 1040 + 64 * kst + dpart);
        kacc[mt][0] = MFMA(af, wkf[0][kst], kacc[mt][0]);
        kacc[mt][1] = MFMA(af, wkf[1][kst], kacc[mt][1]);
        qacc[mt][0] = MFMA(af, wqf[0][kst], qacc[mt][0]);
        qacc[mt][1] = MFMA(af, wqf[1][kst], qacc[mt][1]);
      }
    }
    // per-token norm^2 partials over this wave's 32-j slice
    float npv[16];
#pragma unroll
    for (int mt = 0; mt < 4; ++mt)
#pragma unroll
      for (int r = 0; r < 4; ++r)
        npv[mt * 4 + r] = kacc[mt][0][r] * kacc[mt][0][r] + kacc[mt][1][r] * kacc[mt][1][r];
#pragma unroll
    for (int m = 1; m < 16; m <<= 1)
#pragma unroll
      for (int k = 0; k < 16; ++k) npv[k] += __shfl_xor(npv[k], m);
    normp_s[w][16 * (a >> 2) + 4 * g + (a & 3)] = npv[(a >> 2) * 4 + (a & 3)];
    __syncthreads();   // bar3
    if (tid < 64) {
      float n2 = normp_s[0][tid] + normp_s[1][tid] + normp_s[2][tid] + normp_s[3][tid];
      invn_s[tid] = rsqrtf(fmaxf(n2, 1e-24f));
    }
    __syncthreads();   // bar4

    // ================= scores + online softmax (wave-local, identical across waves) ======
    f32x4_t iv[4];
#pragma unroll
    for (int mt = 0; mt < 4; ++mt)
      iv[mt] = *reinterpret_cast<const f32x4_t*>(invn_s + 16 * mt + 4 * g);
    float wv[4][2][4];
    float tmax[2] = {-3e38f, -3e38f};
#pragma unroll
    for (int mt = 0; mt < 4; ++mt)
#pragma unroll
      for (int nt = 0; nt < 2; ++nt)
#pragma unroll
        for (int r = 0; r < 4; ++r) {
          float s = qacc[mt][nt][r] * iv[mt][r];
          wv[mt][nt][r] = s;
          tmax[nt] = fmaxf(tmax[nt], s);
        }
#pragma unroll
    for (int nt = 0; nt < 2; ++nt) {
      tmax[nt] = fmaxf(tmax[nt], __shfl_xor(tmax[nt], 16));
      tmax[nt] = fmaxf(tmax[nt], __shfl_xor(tmax[nt], 32));
    }
    float mo[2] = {mArr_s[a], mArr_s[a + 16]};
    float mn[2] = {fmaxf(mo[0], tmax[0]), fmaxf(mo[1], tmax[1])};
    float fe[2] = {__expf(mo[0] - mn[0]), __expf(mo[1] - mn[1])};
    float tsum[2] = {0.f, 0.f};
#pragma unroll
    for (int mt = 0; mt < 4; ++mt)
#pragma unroll
      for (int nt = 0; nt < 2; ++nt)
#pragma unroll
        for (int r = 0; r < 4; ++r) {
          float e = __expf(wv[mt][nt][r] - mn[nt]);
          wv[mt][nt][r] = e;
          tsum[nt] += e;
        }
#pragma unroll
    for (int nt = 0; nt < 2; ++nt) {
      tsum[nt] += __shfl_xor(tsum[nt], 16);
      tsum[nt] += __shfl_xor(tsum[nt], 32);
    }
    // each wave writes its own t-quarter (mt = w) of the weight tile
#pragma unroll
    for (int nt = 0; nt < 2; ++nt) {
      half4_t wp;
      wp[0] = (_Float16)wv[w][nt][0]; wp[1] = (_Float16)wv[w][nt][1];
      wp[2] = (_Float16)wv[w][nt][2]; wp[3] = (_Float16)wv[w][nt][3];
      *reinterpret_cast<half4_t*>(wl_raw + (16 * nt + a) * 144 + 32 * w + 8 * g) = wp;
    }
    __syncthreads();   // bar5: weights ready
    if (tid < 16) {    // state update (safe: next mArr read is after next bar4)
      mArr_s[tid] = mn[0];
      mArr_s[tid + 16] = mn[1];
      lArr_s[tid] = lArr_s[tid] * fe[0] + tsum[0];
      lArr_s[tid + 16] = lArr_s[tid + 16] * fe[1] + tsum[1];
    }
    // rescale accumulator rows by per-p factor (broadcast via shfl)
#pragma unroll
    for (int pm = 0; pm < 2; ++pm)
#pragma unroll
      for (int r = 0; r < 4; ++r) {
        float fsh = __shfl(fe[pm], 4 * g + r);
#pragma unroll
        for (int nt = 0; nt < 8; ++nt) acc3[pm][nt][r] *= fsh;
      }
    // ================= GEMM3: acc3[p][d-slice] += w[p][t] * xn[t][d] =================
#pragma unroll
    for (int k2 = 0; k2 < 2; ++k2) {
      half8_t a0 = *reinterpret_cast<const half8_t*>(wl_raw + a * 144 + 64 * k2 + 16 * g);
      half8_t a1 = *reinterpret_cast<const half8_t*>(wl_raw + (a + 16) * 144 + 64 * k2 + 16 * g);
#pragma unroll
      for (int nt = 0; nt < 8; ++nt) {
        half8_t bf = *reinterpret_cast<const half8_t*>(
            xt_raw + (128 * w + 16 * nt + a) * 144 + 64 * k2 + 16 * g);
        acc3[0][nt] = MFMA(a0, bf, acc3[0][nt]);
        acc3[1][nt] = MFMA(a1, bf, acc3[1][nt]);
      }
    }
  }

  __syncthreads();
  float* xb = xbar + ((((size_t)b * NH + h) * NCHUNK + c) * NPAD) * DDIM;
#pragma unroll
  for (int pm = 0; pm < 2; ++pm)
#pragma unroll
    for (int nt = 0; nt < 8; ++nt)
#pragma unroll
      for (int r = 0; r < 4; ++r)
        xb[(size_t)(16 * pm + 4 * g + r) * DDIM + 128 * w + 16 * nt + a] = acc3[pm][nt][r];
  if (tid < 32) {
    size_t mlb = ((((size_t)b * NH + h) * NCHUNK + c) * NPAD + tid) * 2;
    ml[mlb] = mArr_s[tid];
    ml[mlb + 1] = lArr_s[tid];
  }
}

// ---------------- combine chunk partials, apply Wv ----
__global__ __launch_bounds__(256) void reduce_proto(
    const float* __restrict__ ml, const float* __restrict__ xbar,
    const float* __restrict__ Wv, float* __restrict__ proto_t)
{
  const int tid = threadIdx.x;
  const int blk = blockIdx.x;
  const int p = blk % NP;
  const int h = (blk / NP) % NH;
  const int b = blk / (NP * NH);

  __shared__ float fch[NCHUNK];
  __shared__ float LinvS;
  __shared__ float xbs[DDIM];
  __shared__ float part[256];

  if (tid == 0) {
    float mstar = -1e30f;
    for (int cc = 0; cc < NCHUNK; ++cc) {
      size_t idx = ((((size_t)b * NH + h) * NCHUNK + cc) * NPAD + p) * 2;
      mstar = fmaxf(mstar, ml[idx]);
    }
    float L = 0.f;
    for (int cc = 0; cc < NCHUNK; ++cc) {
      size_t idx = ((((size_t)b * NH + h) * NCHUNK + cc) * NPAD + p) * 2;
      float f = expf(ml[idx] - mstar);
      fch[cc] = f;
      L += ml[idx + 1] * f;
    }
    LinvS = 1.f / fmaxf(L, 1e-30f);
  }
  __syncthreads();
  float a0 = 0.f, a1 = 0.f;
  for (int cc = 0; cc < NCHUNK; ++cc) {
    float f = fch[cc];
    const float* src = xbar + ((((size_t)b * NH + h) * NCHUNK + cc) * NPAD + p) * DDIM;
    a0 += f * src[tid];
    a1 += f * src[tid + 256];
  }
  xbs[tid] = a0; xbs[tid + 256] = a1;
  __syncthreads();
  const float Linv = LinvS;
  const int j = tid & 127, halfsel = tid >> 7;
  const float* wrow = Wv + (size_t)(h * HDIM + j) * DDIM + halfsel * 256;
  const float* xh = &xbs[halfsel * 256];
  float s = 0.f;
#pragma unroll 4
  for (int d = 0; d < 256; ++d) s += xh[d] * wrow[d];
  part[tid] = s;
  __syncthreads();
  if (tid < 128) {
    proto_t[((size_t)b * NP + p) * DDIM + h * HDIM + tid] = (part[tid] + part[tid + 128]) * Linv;
  }
}

// ---------------- proto scores, stable top-k, mean, SiLU MLP ----
__global__ __launch_bounds__(256) void final_mlp(
    const float* __restrict__ proto_t, const float* __restrict__ W1, const float* __restrict__ b1,
    const float* __restrict__ W2, const float* __restrict__ b2, float* __restrict__ out)
{
  const int b = blockIdx.x, tid = threadIdx.x;
  __shared__ float pt[NP][DDIM];
  __shared__ float spart[NP][8];
  __shared__ float sc[NP];
  __shared__ int sel[NP];
  __shared__ float zb[DDIM];
  __shared__ float hb[DDIM];
  for (int i = tid; i < NP * DDIM; i += 256) pt[i >> 9][i & 511] = proto_t[(size_t)b * NP * DDIM + i];
  __syncthreads();
  {
    int p = tid >> 3, pr = tid & 7;
    if (p < NP) {
      float s = 0.f;
      for (int k = 0; k < 64; ++k) { float v = pt[p][pr * 64 + k]; s += v * v; }
      spart[p][pr] = s;
    }
  }
  __syncthreads();
  if (tid < NP) {
    float s = 0.f;
    for (int k = 0; k < 8; ++k) s += spart[tid][k];
    sc[tid] = s;
  }
  __syncthreads();
  if (tid < NP) {
    float sv = sc[tid]; int rank = 0;
    for (int q = 0; q < NP; ++q) { float so = sc[q]; if (so > sv || (so == sv && q < tid)) ++rank; }
    sel[tid] = (rank < NTOPK) ? 1 : 0;
  }
  __syncthreads();
  {
    float z0 = 0.f, z1 = 0.f;
#pragma unroll
    for (int p = 0; p < NP; ++p)
      if (sel[p]) { z0 += pt[p][tid]; z1 += pt[p][tid + 256]; }
    zb[tid] = z0 * (1.f / NTOPK); zb[tid + 256] = z1 * (1.f / NTOPK);
  }
  __syncthreads();
#pragma unroll
  for (int i = 0; i < 2; ++i) {
    int jj = tid + i * 256;
    const float* wr = W1 + (size_t)jj * DDIM;
    float s = 0.f;
    for (int d = 0; d < DDIM; ++d) s += zb[d] * wr[d];
    s += b1[jj];
    hb[jj] = s / (1.f + expf(-s));
  }
  __syncthreads();
#pragma unroll
  for (int i = 0; i < 2; ++i) {
    int jj = tid + i * 256;
    const float* wr = W2 + (size_t)jj * DDIM;
    float s = 0.f;
    for (int d = 0; d < DDIM; ++d) s += hb[d] * wr[d];
    out[(size_t)b * DDIM + jj] = s + b2[jj];
  }
}

extern "C" void kernel_launch(void* const* d_in, const int* in_sizes, int n_in,
                              void* d_out, int out_size, void* d_ws, size_t ws_size,
                              hipStream_t stream)
{
  const float* x    = (const float*)d_in[0];
  const float* prt  = (const float*)d_in[1];
  const float* ln_g = (const float*)d_in[2];
  const float* ln_b = (const float*)d_in[3];
  const float* Wq   = (const float*)d_in[4];
  const float* Wk   = (const float*)d_in[5];
  const float* Wv   = (const float*)d_in[6];
  const float* W1   = (const float*)d_in[7];
  const float* b1   = (const float*)d_in[8];
  const float* W2   = (const float*)d_in[9];
  const float* b2   = (const float*)d_in[10];
  float* out = (float*)d_out;
  float* ws = (float*)d_ws;

  float* qhs = ws;                       // 12288
  float* ml  = ws + 12288;               // 32768
  float* xb  = ws + 45056;               // 8388608
  float* pt  = ws + 8433664;             // 98304
  _Float16* wk16  = (_Float16*)(ws + 8531968);   // 262144 halves
  _Float16* wqk16 = (_Float16*)(ws + 8663040);   // 65536 halves

  qh_kernel<<<NP, 256, 0, stream>>>(prt, Wq, qhs);
  wk16_kernel<<<512, 256, 0, stream>>>(Wk, wk16);
  wqk_kernel<<<128, 256, 0, stream>>>(qhs, Wk, wqk16);
  attn2<<<BB * NH * NCHUNK, 256, 0, stream>>>(x, ln_g, ln_b, wk16, wqk16, ml, xb);
  reduce_proto<<<BB * NH * NP, 256, 0, stream>>>(ml, xb, Wv, pt);
  final_mlp<<<BB, 256, 0, stream>>>(pt, W1, b1, W2, b2, out);
}

// Round 3
// 428.305 us; speedup vs baseline: 4.1700x; 1.3905x over previous
//
#include <hip/hip_runtime.h>
#include <hip/hip_bf16.h>

#define BB 8
#define TSEQ 8192
#define DDIM 512
#define NH 4
#define HDIM 128
#define NP 24
#define NPAD 32
#define NTOPK 12
#define NCHUNK 16
#define TCHUNK 512
#define TTILE 32
#define NTILES 16

typedef _Float16 half8_t __attribute__((ext_vector_type(8)));
typedef _Float16 half4_t __attribute__((ext_vector_type(4)));
typedef float f32x4_t __attribute__((ext_vector_type(4)));

#define MFMA(a, b, c) __builtin_amdgcn_mfma_f32_16x16x32_f16((a), (b), (c), 0, 0, 0)

// ws layout (float units):
// qhs    @ 0        (12288)   [H][P][HD] f32, l2norm + 1/TEMP folded
// ml     @ 12288    (32768)   [B][H][16][32][2] f32
// xbar   @ 45056    (8388608) [B][H][16][32][512] f32
// pt     @ 8433664  (98304)   [B][P][D] f32
// wk16   @ 8531968  (262144 f16)  [512][512] f16
// wqk16  @ 8663040  (65536 f16)   [h*32+p][512] f16

// ---------------- Qh precompute ----
__global__ __launch_bounds__(256) void qh_kernel(
    const float* __restrict__ proto, const float* __restrict__ Wq, float* __restrict__ qhs)
{
  const int p = blockIdx.x, tid = threadIdx.x;
  __shared__ float prow[DDIM];
  __shared__ float qp[DDIM];
  __shared__ float np[NH][8];
  __shared__ float nb[NH];
  prow[tid] = proto[(size_t)p * DDIM + tid];
  prow[tid + 256] = proto[(size_t)p * DDIM + tid + 256];
  __syncthreads();
#pragma unroll
  for (int i = 0; i < 2; ++i) {
    int dd = tid + i * 256;
    const float* wr = Wq + (size_t)dd * DDIM;
    float s = 0.f;
    for (int d = 0; d < DDIM; ++d) s += prow[d] * wr[d];
    qp[dd] = s;
  }
  __syncthreads();
  {
    int hh = tid >> 3, pr = tid & 7;
    if (hh < NH) {
      float s = 0.f;
      for (int k = 0; k < 16; ++k) { float v = qp[hh * HDIM + pr * 16 + k]; s += v * v; }
      np[hh][pr] = s;
    }
  }
  __syncthreads();
  if (tid < NH) {
    float s = 0.f;
    for (int k = 0; k < 8; ++k) s += np[tid][k];
    nb[tid] = 1.f / (fmaxf(sqrtf(s), 1e-12f) * 0.07f);
  }
  __syncthreads();
#pragma unroll
  for (int i = 0; i < 2; ++i) {
    int dd = tid + i * 256;
    int hh = dd >> 7, jj = dd & 127;
    qhs[((size_t)hh * NP + p) * HDIM + jj] = qp[dd] * nb[hh];
  }
}

// ---------------- Wk -> f16 copy ----
__global__ __launch_bounds__(256) void wk16_kernel(
    const float* __restrict__ Wk, _Float16* __restrict__ wk16)
{
  const int row = blockIdx.x, tid = threadIdx.x;
  wk16[(size_t)row * 512 + tid]       = (_Float16)Wk[(size_t)row * 512 + tid];
  wk16[(size_t)row * 512 + tid + 256] = (_Float16)Wk[(size_t)row * 512 + tid + 256];
}

// ---------------- Wqk[h*32+p][d] = sum_j qhs[h][p][j] * Wk[h*128+j][d], f16 ----
__global__ __launch_bounds__(256) void wqk_kernel(
    const float* __restrict__ qhs, const float* __restrict__ Wk, _Float16* __restrict__ wqk16)
{
  const int blk = blockIdx.x, tid = threadIdx.x;
  const int p = blk & 31, h = blk >> 5;
  if (p >= NP) {
    wqk16[((size_t)(h * 32 + p)) * 512 + tid] = (_Float16)0.f;
    wqk16[((size_t)(h * 32 + p)) * 512 + tid + 256] = (_Float16)0.f;
    return;
  }
  __shared__ float qv[HDIM];
  if (tid < HDIM) qv[tid] = qhs[((size_t)h * NP + p) * HDIM + tid];
  __syncthreads();
  float s0 = 0.f, s1 = 0.f;
  for (int j = 0; j < HDIM; ++j) {
    float q = qv[j];
    const float* wr = Wk + (size_t)(h * 128 + j) * 512;
    s0 += q * wr[tid];
    s1 += q * wr[tid + 256];
  }
  wqk16[((size_t)(h * 32 + p)) * 512 + tid] = (_Float16)s0;
  wqk16[((size_t)(h * 32 + p)) * 512 + tid + 256] = (_Float16)s1;
}

// ---------------- fused LN + K/scores MFMA + online softmax + MFMA accumulate ----
// block: 512 thr (8 waves). grid: [b(8)][g2(2)][c(16)]. 2 heads per block.
__global__ __launch_bounds__(512, 2) void attn3(
    const float* __restrict__ x, const float* __restrict__ ln_g, const float* __restrict__ ln_b,
    const _Float16* __restrict__ wk16, const _Float16* __restrict__ wqk16,
    float* __restrict__ ml, float* __restrict__ xbar)
{
  const int tid = threadIdx.x;
  const int w = tid >> 6, l = tid & 63;
  const int g = l >> 4, a = l & 15;
  const int blk = blockIdx.x;
  const int c = blk & 15, g2 = (blk >> 4) & 1, b = blk >> 5;

  __shared__ __align__(16) unsigned char xs_raw[32 * 1040];   // [32 t][520 f16]
  __shared__ __align__(16) unsigned char xt_raw[512 * 72];    // [512 d][36 f16], quad-swizzled
  __shared__ __align__(16) unsigned char wl_raw[64 * 80];     // [64 p][40 f16]
  __shared__ float normp_s[8][32];
  __shared__ float invn_s[2][32];
  __shared__ float mArr_s[64], lArr_s[64], fbuf_s[64];

  if (tid < 64) { mArr_s[tid] = -1e30f; lArr_s[tid] = 0.f; }

  f32x4_t acc3[4][4];
  const f32x4_t vzero = {0.f, 0.f, 0.f, 0.f};
#pragma unroll
  for (int mA = 0; mA < 4; ++mA)
#pragma unroll
    for (int nt = 0; nt < 4; ++nt) acc3[mA][nt] = vzero;

  // ln params for this thread's d-slice: d = 4l + 256i
  float4 gq[2], bq[2];
#pragma unroll
  for (int i = 0; i < 2; ++i) {
    gq[i] = reinterpret_cast<const float4*>(ln_g)[l + 64 * i];
    bq[i] = reinterpret_cast<const float4*>(ln_b)[l + 64 * i];
  }

  const float4* xc4 = reinterpret_cast<const float4*>(x) + ((size_t)(b * TSEQ + c * TCHUNK)) * 128;
  // global weight bases (streamed from L2 every k-step)
  const _Float16* wkbase = wk16 + ((size_t)(g2 * 256 + 32 * w + a)) * 512 + g * 8;
  const _Float16* wqbase = wqk16 + ((size_t)(g2 * 64 + 16 * w + a)) * 512 + g * 8;   // only w<4

  float4 praw[4][2];
  // prologue: load tile 0   (token 4w+tt, float4 idx l + 64 i)
#pragma unroll
  for (int tt = 0; tt < 4; ++tt)
#pragma unroll
    for (int i = 0; i < 2; ++i)
      praw[tt][i] = xc4[(size_t)(4 * w + tt) * 128 + l + 64 * i];

  for (int tile = 0; tile < NTILES; ++tile) {
    // ---- LN stats (registers + shuffles only) ----
    float sA[4], sB[4];
#pragma unroll
    for (int tt = 0; tt < 4; ++tt) {
      float4 v0 = praw[tt][0], v1 = praw[tt][1];
      sA[tt] = (v0.x + v0.y) + (v0.z + v0.w) + (v1.x + v1.y) + (v1.z + v1.w);
      sB[tt] = (v0.x * v0.x + v0.y * v0.y) + (v0.z * v0.z + v0.w * v0.w)
             + (v1.x * v1.x + v1.y * v1.y) + (v1.z * v1.z + v1.w * v1.w);
    }
#pragma unroll
    for (int m = 1; m < 64; m <<= 1)
#pragma unroll
      for (int tt = 0; tt < 4; ++tt) { sA[tt] += __shfl_xor(sA[tt], m); sB[tt] += __shfl_xor(sB[tt], m); }
    float muv[4], ivv[4];
#pragma unroll
    for (int tt = 0; tt < 4; ++tt) {
      float mu = sA[tt] * (1.f / 512.f);
      float var = sB[tt] * (1.f / 512.f) - mu * mu;
      muv[tt] = mu; ivv[tt] = rsqrtf(var + 1e-5f);
    }

    __syncthreads();   // barA: prev tile's GEMM reads of xs/xt done

    // ---- normalize in place, write xs (d-contig) ----
#pragma unroll
    for (int tt = 0; tt < 4; ++tt) {
#pragma unroll
      for (int i = 0; i < 2; ++i) {
        float4 v = praw[tt][i];
        v.x = (v.x - muv[tt]) * ivv[tt] * gq[i].x + bq[i].x;
        v.y = (v.y - muv[tt]) * ivv[tt] * gq[i].y + bq[i].y;
        v.z = (v.z - muv[tt]) * ivv[tt] * gq[i].z + bq[i].z;
        v.w = (v.w - muv[tt]) * ivv[tt] * gq[i].w + bq[i].w;
        praw[tt][i] = v;   // now holds xn
        half4_t hx;
        hx[0] = (_Float16)v.x; hx[1] = (_Float16)v.y; hx[2] = (_Float16)v.z; hx[3] = (_Float16)v.w;
        *reinterpret_cast<half4_t*>(xs_raw + (4 * w + tt) * 1040 + 8 * l + 512 * i) = hx;
      }
    }
    // ---- write xt (t-contig half4 per d-row), quad XOR swizzle key=(d>>4)&7 ----
    {
      const float* pf = reinterpret_cast<const float*>(praw);   // [tt][i][e] = pf[tt*8 + i*4 + e]
#pragma unroll
      for (int i = 0; i < 2; ++i)
#pragma unroll
        for (int e = 0; e < 4; ++e) {
          half4_t hv;
          hv[0] = (_Float16)pf[0 * 8 + i * 4 + e];
          hv[1] = (_Float16)pf[1 * 8 + i * 4 + e];
          hv[2] = (_Float16)pf[2 * 8 + i * 4 + e];
          hv[3] = (_Float16)pf[3 * 8 + i * 4 + e];
          int d = 4 * l + 256 * i + e;
          *reinterpret_cast<half4_t*>(xt_raw + d * 72 + 8 * (w ^ ((d >> 4) & 7))) = hv;
        }
    }
    // ---- prefetch next tile's x into praw (latency hidden under GEMMs) ----
    if (tile + 1 < NTILES) {
#pragma unroll
      for (int tt = 0; tt < 4; ++tt)
#pragma unroll
        for (int i = 0; i < 2; ++i)
          praw[tt][i] = xc4[(size_t)((tile + 1) * 32 + 4 * w + tt) * 128 + l + 64 * i];
    }
    __syncthreads();   // barB: xs/xt ready

    // ---- G1 (K for norms) + G2 (raw scores, waves 0-3 only) ----
    f32x4_t kacc[2][2] = {{vzero, vzero}, {vzero, vzero}};
    f32x4_t qacc[2] = {vzero, vzero};
#pragma unroll
    for (int kst = 0; kst < 16; ++kst) {
      half8_t b0 = *reinterpret_cast<const half8_t*>(wkbase + kst * 32);
      half8_t b1 = *reinterpret_cast<const half8_t*>(wkbase + 16 * 512 + kst * 32);
#pragma unroll
      for (int mt = 0; mt < 2; ++mt) {
        half8_t af = *reinterpret_cast<const half8_t*>(xs_raw + (16 * mt + a) * 1040 + kst * 64 + g * 16);
        kacc[mt][0] = MFMA(af, b0, kacc[mt][0]);
        kacc[mt][1] = MFMA(af, b1, kacc[mt][1]);
        if (w < 4) {
          half8_t bq8 = *reinterpret_cast<const half8_t*>(wqbase + kst * 32);
          qacc[mt] = MFMA(af, bq8, qacc[mt]);
        }
      }
    }
    // ---- per-token norm partials over this wave's 32-j slice ----
    {
      float np2[2][4];
#pragma unroll
      for (int mt = 0; mt < 2; ++mt)
#pragma unroll
        for (int r = 0; r < 4; ++r)
          np2[mt][r] = kacc[mt][0][r] * kacc[mt][0][r] + kacc[mt][1][r] * kacc[mt][1][r];
#pragma unroll
      for (int m = 1; m < 16; m <<= 1)
#pragma unroll
        for (int mt = 0; mt < 2; ++mt)
#pragma unroll
          for (int r = 0; r < 4; ++r) np2[mt][r] += __shfl_xor(np2[mt][r], m);
      if (a == 0) {
#pragma unroll
        for (int mt = 0; mt < 2; ++mt)
#pragma unroll
          for (int r = 0; r < 4; ++r) normp_s[w][16 * mt + 4 * g + r] = np2[mt][r];
      }
    }
    __syncthreads();   // barC
    if (tid < 64) {
      int hl = tid >> 5, t = tid & 31;
      float s = normp_s[hl * 4 + 0][t] + normp_s[hl * 4 + 1][t]
              + normp_s[hl * 4 + 2][t] + normp_s[hl * 4 + 3][t];
      invn_s[hl][t] = rsqrtf(fmaxf(s, 1e-24f));
    }
    __syncthreads();   // barD

    // ---- softmax (waves 0-3; col p = 16w + a) ----
    if (w < 4) {
      const int hl = w >> 1;
      const int p = 16 * w + a;
      float sc[2][4];
      float cmax = -3e38f;
#pragma unroll
      for (int mt = 0; mt < 2; ++mt)
#pragma unroll
        for (int r = 0; r < 4; ++r) {
          float s = qacc[mt][r] * invn_s[hl][16 * mt + 4 * g + r];
          sc[mt][r] = s;
          cmax = fmaxf(cmax, s);
        }
      cmax = fmaxf(cmax, __shfl_xor(cmax, 16));
      cmax = fmaxf(cmax, __shfl_xor(cmax, 32));
      float mo = mArr_s[p];
      float mn = fmaxf(mo, cmax);
      float fe = __expf(mo - mn);
      float ls = 0.f;
#pragma unroll
      for (int mt = 0; mt < 2; ++mt) {
        half4_t wp;
#pragma unroll
        for (int r = 0; r < 4; ++r) {
          float e = __expf(sc[mt][r] - mn);
          ls += e;
          wp[r] = (_Float16)e;
        }
        *reinterpret_cast<half4_t*>(wl_raw + p * 80 + 32 * mt + 8 * g) = wp;
      }
      ls += __shfl_xor(ls, 16);
      ls += __shfl_xor(ls, 32);
      if (l < 16) {   // g==0 lane updates state
        mArr_s[p] = mn;
        lArr_s[p] = lArr_s[p] * fe + ls;
        fbuf_s[p] = fe;
      }
    }
    __syncthreads();   // barE: wl + fbuf ready

    // ---- rescale acc + G3: acc[p][d-slice] += wl[p][t] * xn[t][d] ----
#pragma unroll
    for (int mA = 0; mA < 4; ++mA)
#pragma unroll
      for (int r = 0; r < 4; ++r) {
        float f = fbuf_s[16 * mA + 4 * g + r];
#pragma unroll
        for (int nt = 0; nt < 4; ++nt) acc3[mA][nt][r] *= f;
      }
    {
      half8_t wlf[4];
#pragma unroll
      for (int mA = 0; mA < 4; ++mA)
        wlf[mA] = *reinterpret_cast<const half8_t*>(wl_raw + (16 * mA + a) * 80 + 16 * g);
#pragma unroll
      for (int nt = 0; nt < 4; ++nt) {
        const int d = 64 * w + 16 * nt + a;
        const unsigned char* rowp = xt_raw + d * 72;
        const int key = (d >> 4) & 7;
        half4_t lo = *reinterpret_cast<const half4_t*>(rowp + 8 * ((2 * g) ^ key));
        half4_t hi = *reinterpret_cast<const half4_t*>(rowp + 8 * ((2 * g + 1) ^ key));
        half8_t bf;
        bf[0] = lo[0]; bf[1] = lo[1]; bf[2] = lo[2]; bf[3] = lo[3];
        bf[4] = hi[0]; bf[5] = hi[1]; bf[6] = hi[2]; bf[7] = hi[3];
#pragma unroll
        for (int mA = 0; mA < 4; ++mA) acc3[mA][nt] = MFMA(wlf[mA], bf, acc3[mA][nt]);
      }
    }
  }

  __syncthreads();
  // ---- epilogue: xbar + ml ----
#pragma unroll
  for (int mA = 0; mA < 4; ++mA)
#pragma unroll
    for (int r = 0; r < 4; ++r) {
      const int p = 16 * mA + 4 * g + r;
      const int h = 2 * g2 + (p >> 5), ph = p & 31;
      float* xb = xbar + ((((size_t)b * NH + h) * NCHUNK + c) * NPAD + ph) * DDIM;
#pragma unroll
      for (int nt = 0; nt < 4; ++nt) xb[64 * w + 16 * nt + a] = acc3[mA][nt][r];
    }
  if (tid < 64) {
    const int h = 2 * g2 + (tid >> 5), ph = tid & 31;
    size_t mlb = ((((size_t)b * NH + h) * NCHUNK + c) * NPAD + ph) * 2;
    ml[mlb] = mArr_s[tid];
    ml[mlb + 1] = lArr_s[tid];
  }
}

// ---------------- combine chunk partials, apply Wv ----
__global__ __launch_bounds__(256) void reduce_proto(
    const float* __restrict__ ml, const float* __restrict__ xbar,
    const float* __restrict__ Wv, float* __restrict__ proto_t)
{
  const int tid = threadIdx.x;
  const int blk = blockIdx.x;
  const int p = blk % NP;
  const int h = (blk / NP) % NH;
  const int b = blk / (NP * NH);

  __shared__ float fch[NCHUNK];
  __shared__ float LinvS;
  __shared__ float xbs[DDIM];
  __shared__ float part[256];

  if (tid == 0) {
    float mstar = -1e30f;
    for (int cc = 0; cc < NCHUNK; ++cc) {
      size_t idx = ((((size_t)b * NH + h) * NCHUNK + cc) * NPAD + p) * 2;
      mstar = fmaxf(mstar, ml[idx]);
    }
    float L = 0.f;
    for (int cc = 0; cc < NCHUNK; ++cc) {
      size_t idx = ((((size_t)b * NH + h) * NCHUNK + cc) * NPAD + p) * 2;
      float f = expf(ml[idx] - mstar);
      fch[cc] = f;
      L += ml[idx + 1] * f;
    }
    LinvS = 1.f / fmaxf(L, 1e-30f);
  }
  __syncthreads();
  float a0 = 0.f, a1 = 0.f;
  for (int cc = 0; cc < NCHUNK; ++cc) {
    float f = fch[cc];
    const float* src = xbar + ((((size_t)b * NH + h) * NCHUNK + cc) * NPAD + p) * DDIM;
    a0 += f * src[tid];
    a1 += f * src[tid + 256];
  }
  xbs[tid] = a0; xbs[tid + 256] = a1;
  __syncthreads();
  const float Linv = LinvS;
  const int j = tid & 127, halfsel = tid >> 7;
  const float* wrow = Wv + (size_t)(h * HDIM + j) * DDIM + halfsel * 256;
  const float* xh = &xbs[halfsel * 256];
  float s = 0.f;
#pragma unroll 4
  for (int d = 0; d < 256; ++d) s += xh[d] * wrow[d];
  part[tid] = s;
  __syncthreads();
  if (tid < 128) {
    proto_t[((size_t)b * NP + p) * DDIM + h * HDIM + tid] = (part[tid] + part[tid + 128]) * Linv;
  }
}

// ---------------- proto scores, stable top-k, mean, SiLU MLP ----
__global__ __launch_bounds__(256) void final_mlp(
    const float* __restrict__ proto_t, const float* __restrict__ W1, const float* __restrict__ b1,
    const float* __restrict__ W2, const float* __restrict__ b2, float* __restrict__ out)
{
  const int b = blockIdx.x, tid = threadIdx.x;
  __shared__ float pt[NP][DDIM];
  __shared__ float spart[NP][8];
  __shared__ float sc[NP];
  __shared__ int sel[NP];
  __shared__ float zb[DDIM];
  __shared__ float hb[DDIM];
  for (int i = tid; i < NP * DDIM; i += 256) pt[i >> 9][i & 511] = proto_t[(size_t)b * NP * DDIM + i];
  __syncthreads();
  {
    int p = tid >> 3, pr = tid & 7;
    if (p < NP) {
      float s = 0.f;
      for (int k = 0; k < 64; ++k) { float v = pt[p][pr * 64 + k]; s += v * v; }
      spart[p][pr] = s;
    }
  }
  __syncthreads();
  if (tid < NP) {
    float s = 0.f;
    for (int k = 0; k < 8; ++k) s += spart[tid][k];
    sc[tid] = s;
  }
  __syncthreads();
  if (tid < NP) {
    float sv = sc[tid]; int rank = 0;
    for (int q = 0; q < NP; ++q) { float so = sc[q]; if (so > sv || (so == sv && q < tid)) ++rank; }
    sel[tid] = (rank < NTOPK) ? 1 : 0;
  }
  __syncthreads();
  {
    float z0 = 0.f, z1 = 0.f;
#pragma unroll
    for (int p = 0; p < NP; ++p)
      if (sel[p]) { z0 += pt[p][tid]; z1 += pt[p][tid + 256]; }
    zb[tid] = z0 * (1.f / NTOPK); zb[tid + 256] = z1 * (1.f / NTOPK);
  }
  __syncthreads();
#pragma unroll
  for (int i = 0; i < 2; ++i) {
    int jj = tid + i * 256;
    const float* wr = W1 + (size_t)jj * DDIM;
    float s = 0.f;
    for (int d = 0; d < DDIM; ++d) s += zb[d] * wr[d];
    s += b1[jj];
    hb[jj] = s / (1.f + expf(-s));
  }
  __syncthreads();
#pragma unroll
  for (int i = 0; i < 2; ++i) {
    int jj = tid + i * 256;
    const float* wr = W2 + (size_t)jj * DDIM;
    float s = 0.f;
    for (int d = 0; d < DDIM; ++d) s += hb[d] * wr[d];
    out[(size_t)b * DDIM + jj] = s + b2[jj];
  }
}

extern "C" void kernel_launch(void* const* d_in, const int* in_sizes, int n_in,
                              void* d_out, int out_size, void* d_ws, size_t ws_size,
                              hipStream_t stream)
{
  const float* x    = (const float*)d_in[0];
  const float* prt  = (const float*)d_in[1];
  const float* ln_g = (const float*)d_in[2];
  const float* ln_b = (const float*)d_in[3];
  const float* Wq   = (const float*)d_in[4];
  const float* Wk   = (const float*)d_in[5];
  const float* Wv   = (const float*)d_in[6];
  const float* W1   = (const float*)d_in[7];
  const float* b1   = (const float*)d_in[8];
  const float* W2   = (const float*)d_in[9];
  const float* b2   = (const float*)d_in[10];
  float* out = (float*)d_out;
  float* ws = (float*)d_ws;

  float* qhs = ws;                       // 12288
  float* ml  = ws + 12288;               // 32768
  float* xb  = ws + 45056;               // 8388608
  float* pt  = ws + 8433664;             // 98304
  _Float16* wk16  = (_Float16*)(ws + 8531968);   // 262144 halves
  _Float16* wqk16 = (_Float16*)(ws + 8663040);   // 65536 halves

  qh_kernel<<<NP, 256, 0, stream>>>(prt, Wq, qhs);
  wk16_kernel<<<512, 256, 0, stream>>>(Wk, wk16);
  wqk_kernel<<<128, 256, 0, stream>>>(qhs, Wk, wqk16);
  attn3<<<BB * 2 * NCHUNK, 512, 0, stream>>>(x, ln_g, ln_b, wk16, wqk16, ml, xb);
  reduce_proto<<<BB * NH * NP, 256, 0, stream>>>(ml, xb, Wv, pt);
  final_mlp<<<BB, 256, 0, stream>>>(pt, W1, b1, W2, b2, out);
}